// Round 6
// baseline (4702.835 us; speedup 1.0000x reference)
//
#include <hip/hip_runtime.h>
#include <cstdint>

// B=32, S=1024, D=1024 ContractiveSequenceMixer.
// R6: self-announcing h exchange. Per-step WRITE-ONCE slots (1024 x 128KB,
// reusing the dead xh/xl region), pre-filled with sentinel 0xFFC0FFC0
// (NaN|NaN packed bf16 -- unreachable by finite data). Producers fire one
// 8B sc0sc1 store per lane (no ack, no flag); consumers poll the DATA until
// sentinel-free. Removes ~2 fabric RTTs + poll granularity per step vs R5.

#define BATCH 32
#define SEQ   1024
#define DIM   1024
static const size_t BSD = (size_t)BATCH * SEQ * DIM; // 33554432

typedef short  s16x8 __attribute__((ext_vector_type(8)));
typedef unsigned short u16x4 __attribute__((ext_vector_type(4)));
typedef float  f32x4 __attribute__((ext_vector_type(4)));
typedef unsigned u32x4 __attribute__((ext_vector_type(4)));
typedef unsigned u32x2 __attribute__((ext_vector_type(2)));

#define SENT 0xFFC0FFC0u

__device__ __forceinline__ unsigned short f2bf(float f) {
  union { float f; unsigned int u; } v; v.f = f;
  unsigned int r = v.u + 0x7fffu + ((v.u >> 16) & 1u);  // RNE
  return (unsigned short)(r >> 16);
}
__device__ __forceinline__ float bf2f(unsigned short h) {
  union { unsigned int u; float f; } v; v.u = ((unsigned int)h) << 16; return v.f;
}

__device__ __forceinline__ void gload_lds16(const void* g, void* l) {
  __builtin_amdgcn_global_load_lds(
      (const __attribute__((address_space(1))) void*)g,
      (__attribute__((address_space(3))) void*)l, 16, 0, 0);
}

// fabric-coherent (L1/L2-bypass) ops
#define PLOAD(dst, base, IMM)                                              \
  asm volatile("global_load_dwordx4 %0, %1, off offset:" IMM " sc0 sc1"    \
               : "=v"(dst) : "v"(base))
__device__ __forceinline__ void cstore8u(void* p, u32x2 v) {
  asm volatile("global_store_dwordx2 %0, %1, off sc0 sc1"
               :: "v"(p), "v"(v) : "memory");
}
__device__ __forceinline__ void cstore16u(void* p, u32x4 v) {
  asm volatile("global_store_dwordx4 %0, %1, off sc0 sc1"
               :: "v"(p), "v"(v) : "memory");
}

// ---------------- prep kernels ----------------
__global__ void split_x_kernel(const float* __restrict__ x,
                               unsigned short* __restrict__ xh,
                               unsigned short* __restrict__ xl, long n4) {
  long i = (long)blockIdx.x * blockDim.x + threadIdx.x;
  const long stride = (long)gridDim.x * blockDim.x;
  for (; i < n4; i += stride) {
    f32x4 v = *(const f32x4*)&x[i * 4];
    u16x4 vh, vl;
#pragma unroll
    for (int j = 0; j < 4; ++j) {
      unsigned short hb = f2bf(v[j]);
      vh[j] = hb; vl[j] = f2bf(v[j] - bf2f(hb));
    }
    *(u16x4*)&xh[i * 4] = vh;
    *(u16x4*)&xl[i * 4] = vl;
  }
}

__global__ void split_w_kernel(const float* __restrict__ Wg,
                               const float* __restrict__ Wi,
                               unsigned short* __restrict__ wh,
                               unsigned short* __restrict__ wl) {
  long i = (long)blockIdx.x * blockDim.x + threadIdx.x; // 524288 float4 groups
  if (i >= (long)(2048 * 1024 / 4)) return;
  long flat = i * 4;
  int row = (int)(flat >> 10);
  int col = (int)(flat & 1023);
  const float* src = (row < 1024) ? &Wg[(size_t)row * 1024 + col]
                                  : &Wi[(size_t)(row - 1024) * 1024 + col];
  f32x4 v = *(const f32x4*)src;
  u16x4 vh, vl;
#pragma unroll
  for (int j = 0; j < 4; ++j) {
    unsigned short hb = f2bf(v[j]);
    vh[j] = hb; vl[j] = f2bf(v[j] - bf2f(hb));
  }
  *(u16x4*)&wh[flat] = vh;
  *(u16x4*)&wl[flat] = vl;
}

// Fill h slots: slot0 = zeros (h_0), slots 1..1023 = sentinel. 128 MB total.
__global__ void sentinel_kernel(unsigned* hs) {
  long i = (long)blockIdx.x * blockDim.x + threadIdx.x;  // x4-chunk index
  const long stride = (long)gridDim.x * blockDim.x;
  u32x4 z = {0u, 0u, 0u, 0u};
  u32x4 s = {SENT, SENT, SENT, SENT};
  for (; i < 8388608; i += stride) {
    u32x4 v = (i < 8192) ? z : s;
    cstore16u(hs + i * 4, v);
  }
}

// ---------------- fused G/P GEMM (split-bf16, 3-term) ----------------
__global__ __launch_bounds__(256) void gemm_gp_kernel(
    const unsigned short* __restrict__ xh, const unsigned short* __restrict__ xl,
    const unsigned short* __restrict__ wh, const unsigned short* __restrict__ wl,
    const float* __restrict__ bg, const float* __restrict__ bi,
    float* __restrict__ G, float* __restrict__ P) {
  __shared__ unsigned short sAh[128 * 32], sAl[128 * 32], sBh[128 * 32], sBl[128 * 32];
  const int tid = threadIdx.x;
  const int w = tid >> 6, l = tid & 63;
  const int wr = w >> 1, wc = w & 1;
  const int lr = l & 15, lk8 = (l >> 4) * 8;
  const size_t rBase = (size_t)blockIdx.x * 128;
  const int cBase = blockIdx.y * 128;

  f32x4 acc[4][4];
  f32x4 z = {0.f, 0.f, 0.f, 0.f};
#pragma unroll
  for (int m = 0; m < 4; ++m)
#pragma unroll
    for (int n = 0; n < 4; ++n) acc[m][n] = z;

  for (int kb = 0; kb < 32; ++kb) {
    const int k0 = kb * 32;
#pragma unroll
    for (int i = 0; i < 2; ++i) {
      const int chunk = w * 128 + i * 64 + l;
      const int row = chunk >> 2;
      const int c8 = (chunk & 3) * 8;
      gload_lds16(xh + (rBase + row) * 1024 + k0 + c8, &sAh[chunk * 8]);
      gload_lds16(xl + (rBase + row) * 1024 + k0 + c8, &sAl[chunk * 8]);
      gload_lds16(wh + (size_t)(cBase + row) * 1024 + k0 + c8, &sBh[chunk * 8]);
      gload_lds16(wl + (size_t)(cBase + row) * 1024 + k0 + c8, &sBl[chunk * 8]);
    }
    __syncthreads();

    s16x8 ah[4], al[4], bh[4], bl[4];
#pragma unroll
    for (int m = 0; m < 4; ++m) {
      ah[m] = *(const s16x8*)&sAh[(wr * 64 + m * 16 + lr) * 32 + lk8];
      al[m] = *(const s16x8*)&sAl[(wr * 64 + m * 16 + lr) * 32 + lk8];
    }
#pragma unroll
    for (int n = 0; n < 4; ++n) {
      bh[n] = *(const s16x8*)&sBh[(wc * 64 + n * 16 + lr) * 32 + lk8];
      bl[n] = *(const s16x8*)&sBl[(wc * 64 + n * 16 + lr) * 32 + lk8];
    }
#pragma unroll
    for (int m = 0; m < 4; ++m)
#pragma unroll
      for (int n = 0; n < 4; ++n)
        acc[m][n] = __builtin_amdgcn_mfma_f32_16x16x32_bf16(ah[m], bh[n], acc[m][n], 0, 0, 0);
#pragma unroll
    for (int m = 0; m < 4; ++m)
#pragma unroll
      for (int n = 0; n < 4; ++n)
        acc[m][n] = __builtin_amdgcn_mfma_f32_16x16x32_bf16(al[m], bh[n], acc[m][n], 0, 0, 0);
#pragma unroll
    for (int m = 0; m < 4; ++m)
#pragma unroll
      for (int n = 0; n < 4; ++n)
        acc[m][n] = __builtin_amdgcn_mfma_f32_16x16x32_bf16(ah[m], bl[n], acc[m][n], 0, 0, 0);
    __syncthreads();
  }

  const bool isG = (cBase < 1024);
#pragma unroll
  for (int m = 0; m < 4; ++m) {
#pragma unroll
    for (int n = 0; n < 4; ++n) {
      const int col = cBase + wc * 64 + n * 16 + lr;
      const size_t row0 = rBase + wr * 64 + m * 16 + (l >> 4) * 4;
#pragma unroll
      for (int i = 0; i < 4; ++i) {
        float v = acc[m][n][i];
        if (isG) {
          v += bg[col];
          v = 1.f / (1.f + expf(-v));
          G[(row0 + i) * 1024 + col] = v;
        } else {
          v += bi[col - 1024];
          P[(row0 + i) * 1024 + (col - 1024)] = v;
        }
      }
    }
  }
}

// ---------------- persistent recurrence kernel (v6: data-poll) ----------------
// 256 WGs x 256 thr. group g = bid>>5 (batches 4g..4g+3), rank = bid&31
// (e-rows rank*32..+32), wave kq = K-quarter. h slot layout per step:
// [batch(32)][e(1024)] u32 = (hi_bf16<<16)|lo_bf16.
__global__ __launch_bounds__(256, 1) void recur_kernel(
    const float* __restrict__ Ws, const float* __restrict__ bs,
    const float* __restrict__ G, float* out, unsigned* hs) {
  __shared__ float part[2 * 4 * 4 * 32];  // [parity][kq][batch][32 e]
  const int g = blockIdx.x >> 5;
  const int rank = blockIdx.x & 31;
  const int tid = threadIdx.x;
  const int kq = tid >> 6, l = tid & 63;
  const int lr = l & 15, lh4 = l >> 4;

  // ---- Ws fragments -> registers (rank's 32 rows, wave's K-quarter) ----
  s16x8 bhi[2][8], blo[2][8];
#pragma unroll
  for (int nt = 0; nt < 2; ++nt) {
#pragma unroll
    for (int c = 0; c < 8; ++c) {
      const int e = rank * 32 + nt * 16 + lr;
      const int k = kq * 256 + c * 32 + lh4 * 8;
      const float* src = Ws + (size_t)e * DIM + k;
      f32x4 v0 = *(const f32x4*)src;
      f32x4 v1 = *(const f32x4*)(src + 4);
      s16x8 vh, vl;
#pragma unroll
      for (int j = 0; j < 4; ++j) {
        unsigned short hb = f2bf(v0[j]);
        vh[j] = (short)hb;
        vl[j] = (short)f2bf(v0[j] - bf2f(hb));
        unsigned short hb2 = f2bf(v1[j]);
        vh[4 + j] = (short)hb2;
        vl[4 + j] = (short)f2bf(v1[j] - bf2f(hb2));
      }
      bhi[nt][c] = vh; blo[nt][c] = vl;
    }
  }

  // ---- wave0 epilogue state: lane handles (batch=lh4, e=egl..egl+1) ----
  float hold0 = 0.f, hold1 = 0.f;
  float2 bs2 = {0.f, 0.f};
  size_t gpi = 0;
  int bgl = 0, egl = 0;
  if (tid < 64) {
    bgl = g * 4 + lh4;
    egl = rank * 32 + lr * 2;
    bs2 = *(const float2*)&bs[egl];
    gpi = ((size_t)bgl * SEQ) * DIM + egl;
  }
  float2 gA = {0, 0}, pA = {0, 0}, gB = {0, 0}, pB = {0, 0};
  if (tid < 64) { gA = *(const float2*)&G[gpi]; pA = *(const float2*)&out[gpi]; }

  // consumer: element offset within slot (valid for lanes lr<4)
  const int cbase = (g * 4 + lr) * 1024 + kq * 256 + lh4 * 8;
  const int sbase = bgl * 1024 + egl;  // producer (wave0 lanes)

  auto body = [&](int t, float2& gc, float2& pc, float2& gn, float2& pn) {
    // ---- data-poll slot t until sentinel-free ----
    const unsigned* hb = hs + (size_t)t * 32768 + cbase;
    u32x4 pk[16];
    int bad;
    do {
      if (lr < 4) {
        PLOAD(pk[0], hb, "0");    PLOAD(pk[1], hb, "16");
        PLOAD(pk[2], hb, "128");  PLOAD(pk[3], hb, "144");
        PLOAD(pk[4], hb, "256");  PLOAD(pk[5], hb, "272");
        PLOAD(pk[6], hb, "384");  PLOAD(pk[7], hb, "400");
        PLOAD(pk[8], hb, "512");  PLOAD(pk[9], hb, "528");
        PLOAD(pk[10], hb, "640"); PLOAD(pk[11], hb, "656");
        PLOAD(pk[12], hb, "768"); PLOAD(pk[13], hb, "784");
        PLOAD(pk[14], hb, "896"); PLOAD(pk[15], hb, "912");
      }
      asm volatile("s_waitcnt vmcnt(0)" ::: "memory");
      bad = 0;
      if (lr < 4) {
#pragma unroll
        for (int i = 0; i < 16; ++i)
#pragma unroll
          for (int j = 0; j < 4; ++j) bad |= (pk[i][j] == SENT);
      }
    } while (__any(bad));
    __builtin_amdgcn_sched_barrier(0);

    // ---- unpack (hi<<16|lo) -> A frags; rows lr>=4 are zero ----
    s16x8 ah[8], al[8];
    if (lr < 4) {
#pragma unroll
      for (int c = 0; c < 8; ++c) {
        u32x4 a = pk[2 * c], b2 = pk[2 * c + 1];
        union { unsigned u[4]; s16x8 v; } hh, ll;
        hh.u[0] = (a[0] >> 16) | (a[1] & 0xFFFF0000u);
        hh.u[1] = (a[2] >> 16) | (a[3] & 0xFFFF0000u);
        hh.u[2] = (b2[0] >> 16) | (b2[1] & 0xFFFF0000u);
        hh.u[3] = (b2[2] >> 16) | (b2[3] & 0xFFFF0000u);
        ll.u[0] = (a[0] & 0xFFFFu) | (a[1] << 16);
        ll.u[1] = (a[2] & 0xFFFFu) | (a[3] << 16);
        ll.u[2] = (b2[0] & 0xFFFFu) | (b2[1] << 16);
        ll.u[3] = (b2[2] & 0xFFFFu) | (b2[3] << 16);
        ah[c] = hh.v; al[c] = ll.v;
      }
    } else {
      s16x8 z8 = {0, 0, 0, 0, 0, 0, 0, 0};
#pragma unroll
      for (int c = 0; c < 8; ++c) { ah[c] = z8; al[c] = z8; }
    }

    // ---- prefetch g,p for t+1 (plain cached loads; resolve during MFMA) ----
    if (tid < 64) {
      const size_t gpn = gpi + ((t + 1 < SEQ) ? DIM : 0);
      gn = *(const float2*)&G[gpn];
      pn = *(const float2*)&out[gpn];
    }

    // ---- 3-term split-bf16 MFMA ----
    f32x4 z = {0.f, 0.f, 0.f, 0.f};
    f32x4 aA[2], aB[2], aC[2];
#pragma unroll
    for (int nt = 0; nt < 2; ++nt) { aA[nt] = z; aB[nt] = z; aC[nt] = z; }
#pragma unroll
    for (int c = 0; c < 8; ++c) {
#pragma unroll
      for (int nt = 0; nt < 2; ++nt) {
        aA[nt] = __builtin_amdgcn_mfma_f32_16x16x32_bf16(ah[c], bhi[nt][c], aA[nt], 0, 0, 0);
        aB[nt] = __builtin_amdgcn_mfma_f32_16x16x32_bf16(al[c], bhi[nt][c], aB[nt], 0, 0, 0);
        aC[nt] = __builtin_amdgcn_mfma_f32_16x16x32_bf16(ah[c], blo[nt][c], aC[nt], 0, 0, 0);
      }
    }

    // ---- partials to LDS (valid batches: lanes lh4==0, regs i=0..3) ----
    if (lh4 == 0) {
#pragma unroll
      for (int nt = 0; nt < 2; ++nt) {
        f32x4 v = aA[nt] + aB[nt] + aC[nt];
#pragma unroll
        for (int i = 0; i < 4; ++i)
          part[(t & 1) * 512 + kq * 128 + i * 32 + nt * 16 + lr] = v[i];
      }
    }
    asm volatile("s_waitcnt lgkmcnt(0)" ::: "memory");
    __builtin_amdgcn_s_barrier();
    __builtin_amdgcn_sched_barrier(0);

    // ---- wave0: K-reduce + epilogue + publish (fire-and-forget) ----
    if (tid < 64) {
      const int b = lh4, e2 = lr * 2;
      const float* pp = &part[(t & 1) * 512 + b * 32 + e2];
      float2 r0 = *(const float2*)&pp[0];
      float2 r1 = *(const float2*)&pp[128];
      float2 r2 = *(const float2*)&pp[256];
      float2 r3 = *(const float2*)&pp[384];
      const float s0 = r0.x + r1.x + r2.x + r3.x;
      const float s1 = r0.y + r1.y + r2.y + r3.y;
      const float mix0 = s0 + bs2.x + pc.x;
      const float mix1 = s1 + bs2.y + pc.y;
      const float h0 = gc.x * mix0 + (1.f - gc.x) * hold0;
      const float h1 = gc.y * mix1 + (1.f - gc.y) * hold1;
      hold0 = h0; hold1 = h1;

      if (t < SEQ - 1) {
        const unsigned short hb0 = f2bf(h0), hb1 = f2bf(h1);
        const unsigned short lb0 = f2bf(h0 - bf2f(hb0));
        const unsigned short lb1 = f2bf(h1 - bf2f(hb1));
        u32x2 pv;
        pv[0] = ((unsigned)hb0 << 16) | (unsigned)lb0;
        pv[1] = ((unsigned)hb1 << 16) | (unsigned)lb1;
        cstore8u(hs + (size_t)(t + 1) * 32768 + sbase, pv);
      }

      float2 ev; ev.x = h0; ev.y = h1;
      *(float2*)&out[gpi] = ev;  // emitted (overwrites consumed P slot)
      if (t == SEQ - 1)
        *(float2*)&out[BSD + (size_t)bgl * DIM + egl] = ev;
      gpi += ((t + 1 < SEQ) ? DIM : 0);
    }
  };

#pragma unroll 1
  for (int t = 0; t < SEQ; t += 2) {
    body(t, gA, pA, gB, pB);
    body(t + 1, gB, pB, gA, pA);
  }
}

// ---------------- launch ----------------
extern "C" void kernel_launch(void* const* d_in, const int* in_sizes, int n_in,
                              void* d_out, int out_size, void* d_ws, size_t ws_size,
                              hipStream_t stream) {
  (void)in_sizes; (void)n_in; (void)out_size; (void)ws_size;
  const float* x  = (const float*)d_in[0];
  const float* Wg = (const float*)d_in[1];
  const float* bg = (const float*)d_in[2];
  const float* Ws = (const float*)d_in[3];
  const float* bs = (const float*)d_in[4];
  const float* Wi = (const float*)d_in[5];
  const float* bi = (const float*)d_in[6];
  float* out = (float*)d_out;
  char* ws = (char*)d_ws;

  unsigned short* xh = (unsigned short*)(ws);              // 64 MB
  unsigned short* xl = (unsigned short*)(ws + 67108864);   // 64 MB
  unsigned short* wh = (unsigned short*)(ws + 134217728);  // 4 MB (dead after gemm)
  unsigned short* wl = (unsigned short*)(ws + 138412032);  // 4 MB (dead after gemm)
  float*          G  = (float*)(ws + 142606336);           // 128 MB
  unsigned*       hs = (unsigned*)(ws);                    // 128 MB: 1024 slots
                                                           // (reuses xh/xl AFTER gemm)

  hipLaunchKernelGGL(split_x_kernel, dim3(4096), dim3(256), 0, stream,
                     x, xh, xl, (long)(BSD / 4));
  hipLaunchKernelGGL(split_w_kernel, dim3(2048), dim3(256), 0, stream, Wg, Wi, wh, wl);
  hipLaunchKernelGGL(gemm_gp_kernel, dim3(256, 16), dim3(256), 0, stream,
                     xh, xl, wh, wl, bg, bi, G, out);
  hipLaunchKernelGGL(sentinel_kernel, dim3(4096), dim3(256), 0, stream, hs);
  hipLaunchKernelGGL(recur_kernel, dim3(256), dim3(256), 0, stream,
                     Ws, bs, G, out, hs);
}

// Round 7
// 3882.774 us; speedup vs baseline: 1.2112x; 1.2112x over previous
//
#include <hip/hip_runtime.h>
#include <cstdint>

// B=32, S=1024, D=1024 ContractiveSequenceMixer.
// R7: R5's flag-poll structure with the PRODUCER ACK REMOVED.
//  - Producer: h-stores then flag store, all fire-and-forget (no vmcnt).
//  - Consumer: cheap 64B flag poll -> load 4KB once -> SENTINEL-VERIFY the
//    loaded registers (0xFFC0FFC0 = NaN|NaN, unreachable for finite h);
//    reload only on the rare ordering violation.
//  - h lives in write-once per-step slots: [1024 t][32 b][1024 e] ushort,
//    hi plane + lo plane = 128 MB reusing the dead xh/xl region.
// (R6 lesson: poll cheap, transfer once — full-data polling saturated L3.)

#define BATCH 32
#define SEQ   1024
#define DIM   1024
static const size_t BSD = (size_t)BATCH * SEQ * DIM; // 33554432

typedef short  s16x8 __attribute__((ext_vector_type(8)));
typedef unsigned short u16x4 __attribute__((ext_vector_type(4)));
typedef float  f32x4 __attribute__((ext_vector_type(4)));
typedef unsigned u32x4 __attribute__((ext_vector_type(4)));

#define SENT 0xFFC0FFC0u

__device__ __forceinline__ unsigned short f2bf(float f) {
  union { float f; unsigned int u; } v; v.f = f;
  unsigned int r = v.u + 0x7fffu + ((v.u >> 16) & 1u);  // RNE
  return (unsigned short)(r >> 16);
}
__device__ __forceinline__ float bf2f(unsigned short h) {
  union { unsigned int u; float f; } v; v.u = ((unsigned int)h) << 16; return v.f;
}

__device__ __forceinline__ void gload_lds16(const void* g, void* l) {
  __builtin_amdgcn_global_load_lds(
      (const __attribute__((address_space(1))) void*)g,
      (__attribute__((address_space(3))) void*)l, 16, 0, 0);
}

// ---- fabric-coherent (L1/L2-bypass) ops ----
#define HLOAD(dst, base, IMM)                                              \
  asm volatile("global_load_dwordx4 %0, %1, off offset:" IMM " sc0 sc1"    \
               : "=v"(dst) : "v"(base))
#define HL8(arr, base)        \
  HLOAD(arr[0], base, "0");   \
  HLOAD(arr[1], base, "64");  \
  HLOAD(arr[2], base, "128"); \
  HLOAD(arr[3], base, "192"); \
  HLOAD(arr[4], base, "256"); \
  HLOAD(arr[5], base, "320"); \
  HLOAD(arr[6], base, "384"); \
  HLOAD(arr[7], base, "448")

__device__ __forceinline__ void cstore4u(void* p, unsigned v) {
  asm volatile("global_store_dword %0, %1, off sc0 sc1"
               :: "v"(p), "v"(v) : "memory");
}
__device__ __forceinline__ void cstore4(void* p, int v) {
  asm volatile("global_store_dword %0, %1, off sc0 sc1"
               :: "v"(p), "v"(v) : "memory");
}
__device__ __forceinline__ void cstore16u(void* p, u32x4 v) {
  asm volatile("global_store_dwordx4 %0, %1, off sc0 sc1"
               :: "v"(p), "v"(v) : "memory");
}
__device__ __forceinline__ int cload4(const void* p) {
  int v;
  asm volatile("global_load_dword %0, %1, off sc0 sc1\n\ts_waitcnt vmcnt(0)"
               : "=v"(v) : "v"(p) : "memory");
  return v;
}

__device__ __forceinline__ int is_sent(s16x8 v) {
  union { s16x8 s; u32x4 u; } x; x.s = v;
  return (x.u[0] == SENT) | (x.u[1] == SENT) | (x.u[2] == SENT) | (x.u[3] == SENT);
}

// ---------------- prep kernels ----------------
__global__ void split_x_kernel(const float* __restrict__ x,
                               unsigned short* __restrict__ xh,
                               unsigned short* __restrict__ xl, long n4) {
  long i = (long)blockIdx.x * blockDim.x + threadIdx.x;
  const long stride = (long)gridDim.x * blockDim.x;
  for (; i < n4; i += stride) {
    f32x4 v = *(const f32x4*)&x[i * 4];
    u16x4 vh, vl;
#pragma unroll
    for (int j = 0; j < 4; ++j) {
      unsigned short hb = f2bf(v[j]);
      vh[j] = hb; vl[j] = f2bf(v[j] - bf2f(hb));
    }
    *(u16x4*)&xh[i * 4] = vh;
    *(u16x4*)&xl[i * 4] = vl;
  }
}

__global__ void split_w_kernel(const float* __restrict__ Wg,
                               const float* __restrict__ Wi,
                               unsigned short* __restrict__ wh,
                               unsigned short* __restrict__ wl) {
  long i = (long)blockIdx.x * blockDim.x + threadIdx.x; // 524288 float4 groups
  if (i >= (long)(2048 * 1024 / 4)) return;
  long flat = i * 4;
  int row = (int)(flat >> 10);
  int col = (int)(flat & 1023);
  const float* src = (row < 1024) ? &Wg[(size_t)row * 1024 + col]
                                  : &Wi[(size_t)(row - 1024) * 1024 + col];
  f32x4 v = *(const f32x4*)src;
  u16x4 vh, vl;
#pragma unroll
  for (int j = 0; j < 4; ++j) {
    unsigned short hb = f2bf(v[j]);
    vh[j] = hb; vl[j] = f2bf(v[j] - bf2f(hb));
  }
  *(u16x4*)&wh[flat] = vh;
  *(u16x4*)&wl[flat] = vl;
}

// Fill both h planes: slot0 = zeros (h_0), slots 1..1023 = sentinel.
// Also zero the 4096-int flag array. All sc0sc1.
__global__ void sentinel_kernel(unsigned* hsH, unsigned* hsL, int* flags) {
  long i = (long)blockIdx.x * blockDim.x + threadIdx.x;  // x4-dword chunks
  const long stride = (long)gridDim.x * blockDim.x;
  u32x4 z = {0u, 0u, 0u, 0u};
  u32x4 s = {SENT, SENT, SENT, SENT};
  for (long k = i; k < 4194304; k += stride) {  // 16M dwords/plane / 4
    u32x4 v = (k < 4096) ? z : s;               // slot0 = 4096 chunks
    cstore16u(hsH + k * 4, v);
    cstore16u(hsL + k * 4, v);
  }
  if (i < 4096) cstore4(flags + i, 0);
}

// ---------------- fused G/P GEMM (split-bf16, 3-term) ----------------
__global__ __launch_bounds__(256) void gemm_gp_kernel(
    const unsigned short* __restrict__ xh, const unsigned short* __restrict__ xl,
    const unsigned short* __restrict__ wh, const unsigned short* __restrict__ wl,
    const float* __restrict__ bg, const float* __restrict__ bi,
    float* __restrict__ G, float* __restrict__ P) {
  __shared__ unsigned short sAh[128 * 32], sAl[128 * 32], sBh[128 * 32], sBl[128 * 32];
  const int tid = threadIdx.x;
  const int w = tid >> 6, l = tid & 63;
  const int wr = w >> 1, wc = w & 1;
  const int lr = l & 15, lk8 = (l >> 4) * 8;
  const size_t rBase = (size_t)blockIdx.x * 128;
  const int cBase = blockIdx.y * 128;

  f32x4 acc[4][4];
  f32x4 z = {0.f, 0.f, 0.f, 0.f};
#pragma unroll
  for (int m = 0; m < 4; ++m)
#pragma unroll
    for (int n = 0; n < 4; ++n) acc[m][n] = z;

  for (int kb = 0; kb < 32; ++kb) {
    const int k0 = kb * 32;
#pragma unroll
    for (int i = 0; i < 2; ++i) {
      const int chunk = w * 128 + i * 64 + l;
      const int row = chunk >> 2;
      const int c8 = (chunk & 3) * 8;
      gload_lds16(xh + (rBase + row) * 1024 + k0 + c8, &sAh[chunk * 8]);
      gload_lds16(xl + (rBase + row) * 1024 + k0 + c8, &sAl[chunk * 8]);
      gload_lds16(wh + (size_t)(cBase + row) * 1024 + k0 + c8, &sBh[chunk * 8]);
      gload_lds16(wl + (size_t)(cBase + row) * 1024 + k0 + c8, &sBl[chunk * 8]);
    }
    __syncthreads();

    s16x8 ah[4], al[4], bh[4], bl[4];
#pragma unroll
    for (int m = 0; m < 4; ++m) {
      ah[m] = *(const s16x8*)&sAh[(wr * 64 + m * 16 + lr) * 32 + lk8];
      al[m] = *(const s16x8*)&sAl[(wr * 64 + m * 16 + lr) * 32 + lk8];
    }
#pragma unroll
    for (int n = 0; n < 4; ++n) {
      bh[n] = *(const s16x8*)&sBh[(wc * 64 + n * 16 + lr) * 32 + lk8];
      bl[n] = *(const s16x8*)&sBl[(wc * 64 + n * 16 + lr) * 32 + lk8];
    }
#pragma unroll
    for (int m = 0; m < 4; ++m)
#pragma unroll
      for (int n = 0; n < 4; ++n)
        acc[m][n] = __builtin_amdgcn_mfma_f32_16x16x32_bf16(ah[m], bh[n], acc[m][n], 0, 0, 0);
#pragma unroll
    for (int m = 0; m < 4; ++m)
#pragma unroll
      for (int n = 0; n < 4; ++n)
        acc[m][n] = __builtin_amdgcn_mfma_f32_16x16x32_bf16(al[m], bh[n], acc[m][n], 0, 0, 0);
#pragma unroll
    for (int m = 0; m < 4; ++m)
#pragma unroll
      for (int n = 0; n < 4; ++n)
        acc[m][n] = __builtin_amdgcn_mfma_f32_16x16x32_bf16(ah[m], bl[n], acc[m][n], 0, 0, 0);
    __syncthreads();
  }

  const bool isG = (cBase < 1024);
#pragma unroll
  for (int m = 0; m < 4; ++m) {
#pragma unroll
    for (int n = 0; n < 4; ++n) {
      const int col = cBase + wc * 64 + n * 16 + lr;
      const size_t row0 = rBase + wr * 64 + m * 16 + (l >> 4) * 4;
#pragma unroll
      for (int i = 0; i < 4; ++i) {
        float v = acc[m][n][i];
        if (isG) {
          v += bg[col];
          v = 1.f / (1.f + expf(-v));
          G[(row0 + i) * 1024 + col] = v;
        } else {
          v += bi[col - 1024];
          P[(row0 + i) * 1024 + (col - 1024)] = v;
        }
      }
    }
  }
}

// ---------------- persistent recurrence kernel (v7) ----------------
// 256 WGs x 256 thr. group g = bid>>5 (batches 4g..4g+3), rank = bid&31
// (e-rows rank*32..+32), wave kq = K-quarter (polls its 8 producers' flags).
// Slots: hsH/hsL [t][32 b][1024 e] ushort. Producer: data + flag stores,
// NO ack. Consumer: flag poll -> load once -> sentinel-verify -> rare reload.
__global__ __launch_bounds__(256) void recur_kernel(
    const float* __restrict__ Ws, const float* __restrict__ bs,
    const float* __restrict__ G, float* out,
    unsigned short* hsH, unsigned short* hsL, int* flags) {
  __shared__ float part[2 * 4 * 4 * 32];  // [parity][kq][batch][32 e]
  const int g = blockIdx.x >> 5;
  const int rank = blockIdx.x & 31;
  const int tid = threadIdx.x;
  const int kq = tid >> 6, l = tid & 63;
  const int lr = l & 15, lh4 = l >> 4;

  // ---- Ws fragments -> registers (rank's 32 rows, wave's K-quarter) ----
  s16x8 bhi[2][8], blo[2][8];
#pragma unroll
  for (int nt = 0; nt < 2; ++nt) {
#pragma unroll
    for (int c = 0; c < 8; ++c) {
      const int e = rank * 32 + nt * 16 + lr;
      const int k = kq * 256 + c * 32 + lh4 * 8;
      const float* src = Ws + (size_t)e * DIM + k;
      f32x4 v0 = *(const f32x4*)src;
      f32x4 v1 = *(const f32x4*)(src + 4);
      s16x8 vh, vl;
#pragma unroll
      for (int j = 0; j < 4; ++j) {
        unsigned short hb = f2bf(v0[j]);
        vh[j] = (short)hb;
        vl[j] = (short)f2bf(v0[j] - bf2f(hb));
        unsigned short hb2 = f2bf(v1[j]);
        vh[4 + j] = (short)hb2;
        vl[4 + j] = (short)f2bf(v1[j] - bf2f(hb2));
      }
      bhi[nt][c] = vh; blo[nt][c] = vl;
    }
  }

  // ---- wave0 epilogue state: lane handles (batch=lh4, e=egl..egl+1) ----
  float hold0 = 0.f, hold1 = 0.f;
  float2 bs2 = {0.f, 0.f};
  size_t gpi = 0;
  int bgl = 0, egl = 0;
  if (tid < 64) {
    bgl = g * 4 + lh4;
    egl = rank * 32 + lr * 2;
    bs2 = *(const float2*)&bs[egl];
    gpi = ((size_t)bgl * SEQ) * DIM + egl;
  }
  float2 gA = {0, 0}, pA = {0, 0}, gB = {0, 0}, pB = {0, 0};
  if (tid < 64) { gA = *(const float2*)&G[gpi]; pA = *(const float2*)&out[gpi]; }

  // consumer: element offset within slot (valid for lanes lr<4; batch = lr)
  const int cbase = (g * 4 + lr) * 1024 + kq * 256 + lh4 * 8;
  const int sbase = bgl * 1024 + egl;  // producer (wave0 lanes)
  const int* fp = flags + ((g << 5) + (kq << 3) + (l & 7)) * 16;
  int* myflag = flags + ((g << 5) + rank) * 16;

  auto body = [&](int t, float2& gc, float2& pc, float2& gn, float2& pn) {
    // ---- poll own 8 producers' flags (cheap 4B probes) ----
    {
      int v;
      do { v = cload4(fp); } while (__any(v < t));
    }
    __builtin_amdgcn_sched_barrier(0);

    // ---- load h_t fragments ONCE; verify sentinel; rare reload ----
    const unsigned short* Hh = hsH + (size_t)t * 32768 + cbase;
    const unsigned short* Hl = hsL + (size_t)t * 32768 + cbase;
    s16x8 ah[8], al[8];
    if (lr < 4) {
      HL8(ah, Hh);
      HL8(al, Hl);
    } else {
      s16x8 z8 = {0, 0, 0, 0, 0, 0, 0, 0};
#pragma unroll
      for (int c = 0; c < 8; ++c) { ah[c] = z8; al[c] = z8; }
    }
    for (;;) {
      asm volatile("s_waitcnt vmcnt(0)" ::: "memory");
      __builtin_amdgcn_sched_barrier(0);
      int bad = 0;
      if (lr < 4) {
#pragma unroll
        for (int c = 0; c < 8; ++c) bad |= is_sent(ah[c]) | is_sent(al[c]);
      }
      if (!__any(bad)) break;
      if (lr < 4) { HL8(ah, Hh); HL8(al, Hl); }
    }
    __builtin_amdgcn_sched_barrier(0);

    // ---- prefetch g,p for t+1 (plain cached loads; resolve during MFMA) ----
    if (tid < 64) {
      const size_t gpn = gpi + ((t + 1 < SEQ) ? DIM : 0);
      gn = *(const float2*)&G[gpn];
      pn = *(const float2*)&out[gpn];
    }

    // ---- 3-term split-bf16 MFMA (A rows = batches, 4 valid) ----
    f32x4 z = {0.f, 0.f, 0.f, 0.f};
    f32x4 aA[2], aB[2], aC[2];
#pragma unroll
    for (int nt = 0; nt < 2; ++nt) { aA[nt] = z; aB[nt] = z; aC[nt] = z; }
#pragma unroll
    for (int c = 0; c < 8; ++c) {
#pragma unroll
      for (int nt = 0; nt < 2; ++nt) {
        aA[nt] = __builtin_amdgcn_mfma_f32_16x16x32_bf16(ah[c], bhi[nt][c], aA[nt], 0, 0, 0);
        aB[nt] = __builtin_amdgcn_mfma_f32_16x16x32_bf16(al[c], bhi[nt][c], aB[nt], 0, 0, 0);
        aC[nt] = __builtin_amdgcn_mfma_f32_16x16x32_bf16(ah[c], blo[nt][c], aC[nt], 0, 0, 0);
      }
    }

    // ---- partials to LDS (valid batches: lanes lh4==0, regs i=0..3) ----
    if (lh4 == 0) {
#pragma unroll
      for (int nt = 0; nt < 2; ++nt) {
        f32x4 v = aA[nt] + aB[nt] + aC[nt];
#pragma unroll
        for (int i = 0; i < 4; ++i)
          part[(t & 1) * 512 + kq * 128 + i * 32 + nt * 16 + lr] = v[i];
      }
    }
    asm volatile("s_waitcnt lgkmcnt(0)" ::: "memory");
    __builtin_amdgcn_s_barrier();
    __builtin_amdgcn_sched_barrier(0);

    // ---- wave0: K-reduce + epilogue + publish (all fire-and-forget) ----
    if (tid < 64) {
      const int b = lh4, e2 = lr * 2;
      const float* pp = &part[(t & 1) * 512 + b * 32 + e2];
      float2 r0 = *(const float2*)&pp[0];
      float2 r1 = *(const float2*)&pp[128];
      float2 r2 = *(const float2*)&pp[256];
      float2 r3 = *(const float2*)&pp[384];
      const float s0 = r0.x + r1.x + r2.x + r3.x;
      const float s1 = r0.y + r1.y + r2.y + r3.y;
      const float mix0 = s0 + bs2.x + pc.x;
      const float mix1 = s1 + bs2.y + pc.y;
      const float h0 = gc.x * mix0 + (1.f - gc.x) * hold0;
      const float h1 = gc.y * mix1 + (1.f - gc.y) * hold1;
      hold0 = h0; hold1 = h1;

      if (t < SEQ - 1) {
        const unsigned short hb0 = f2bf(h0), hb1 = f2bf(h1);
        const unsigned short lb0 = f2bf(h0 - bf2f(hb0));
        const unsigned short lb1 = f2bf(h1 - bf2f(hb1));
        const size_t so = (size_t)(t + 1) * 32768 + sbase;
        cstore4u(hsH + so, (unsigned)hb0 | ((unsigned)hb1 << 16));
        cstore4u(hsL + so, (unsigned)lb0 | ((unsigned)lb1 << 16));
        // flag store: NO vmcnt ack — consumer's sentinel-verify covers the
        // (rare) case where the flag outruns the data at the fabric.
        if (l == 0) cstore4(myflag, t + 1);
      }

      float2 ev; ev.x = h0; ev.y = h1;
      *(float2*)&out[gpi] = ev;  // emitted (overwrites consumed P slot)
      if (t == SEQ - 1)
        *(float2*)&out[BSD + (size_t)bgl * DIM + egl] = ev;
      gpi += ((t + 1 < SEQ) ? DIM : 0);
    }
  };

#pragma unroll 1
  for (int t = 0; t < SEQ; t += 2) {
    body(t, gA, pA, gB, pB);
    body(t + 1, gB, pB, gA, pA);
  }
}

// ---------------- launch ----------------
extern "C" void kernel_launch(void* const* d_in, const int* in_sizes, int n_in,
                              void* d_out, int out_size, void* d_ws, size_t ws_size,
                              hipStream_t stream) {
  (void)in_sizes; (void)n_in; (void)out_size; (void)ws_size;
  const float* x  = (const float*)d_in[0];
  const float* Wg = (const float*)d_in[1];
  const float* bg = (const float*)d_in[2];
  const float* Ws = (const float*)d_in[3];
  const float* bs = (const float*)d_in[4];
  const float* Wi = (const float*)d_in[5];
  const float* bi = (const float*)d_in[6];
  float* out = (float*)d_out;
  char* ws = (char*)d_ws;

  unsigned short* xh = (unsigned short*)(ws);              // 64 MB
  unsigned short* xl = (unsigned short*)(ws + 67108864);   // 64 MB
  unsigned short* wh = (unsigned short*)(ws + 134217728);  // 4 MB (dead after gemm)
  unsigned short* wl = (unsigned short*)(ws + 138412032);  // 4 MB (dead after gemm)
  float*          G  = (float*)(ws + 142606336);           // 128 MB
  // recurrence state (written only AFTER gemm by sentinel_kernel):
  unsigned short* hsH  = (unsigned short*)(ws);             // 64 MB slots (hi)
  unsigned short* hsL  = (unsigned short*)(ws + 67108864);  // 64 MB slots (lo)
  int*            flags= (int*)(ws + 134217728);            // 16 KB (over wh)

  hipLaunchKernelGGL(split_x_kernel, dim3(4096), dim3(256), 0, stream,
                     x, xh, xl, (long)(BSD / 4));
  hipLaunchKernelGGL(split_w_kernel, dim3(2048), dim3(256), 0, stream, Wg, Wi, wh, wl);
  hipLaunchKernelGGL(gemm_gp_kernel, dim3(256, 16), dim3(256), 0, stream,
                     xh, xl, wh, wl, bg, bi, G, out);
  hipLaunchKernelGGL(sentinel_kernel, dim3(4096), dim3(256), 0, stream,
                     (unsigned*)hsH, (unsigned*)hsL, flags);
  hipLaunchKernelGGL(recur_kernel, dim3(256), dim3(256), 0, stream,
                     Ws, bs, G, out, hsH, hsL, flags);
}